// Round 3
// baseline (872.320 us; speedup 1.0000x reference)
//
#include <hip/hip_runtime.h>
#include <cstdint>
#include <cstddef>

// Problem constants
#define CIN   192
#define COUT  192
#define KCB   1024
#define HWSZ  4096            // 64*64
#define NPIX  32768           // 8*64*64
#define LOGIT_SCALE_F 13.856406460551018f

// ---------------------------------------------------------------------------
// JAX threefry2x32 (key = (0,42)), partitionable stream: bits(i) = o0 ^ o1 of
// threefry2x32((k1,k2), (hi32(i)=0, lo32(i)=i))  [validated: rounds 1-2
// passed => gumbel stream is argmax-exact for all 32768 pixels]
// ---------------------------------------------------------------------------
__device__ __forceinline__ void threefry_0_42(uint32_t x0, uint32_t x1,
                                              uint32_t& o0, uint32_t& o1) {
  const uint32_t ks0 = 0u;
  const uint32_t ks1 = 42u;
  const uint32_t ks2 = 0x1BD11BDAu ^ 0u ^ 42u;
  x0 += ks0; x1 += ks1;
#define TFR(r) { x0 += x1; x1 = (x1 << (r)) | (x1 >> (32 - (r))); x1 ^= x0; }
  TFR(13) TFR(15) TFR(26) TFR(6)
  x0 += ks1; x1 += ks2 + 1u;
  TFR(17) TFR(29) TFR(16) TFR(24)
  x0 += ks2; x1 += ks0 + 2u;
  TFR(13) TFR(15) TFR(26) TFR(6)
  x0 += ks0; x1 += ks1 + 3u;
  TFR(17) TFR(29) TFR(16) TFR(24)
  x0 += ks1; x1 += ks2 + 4u;
  TFR(13) TFR(15) TFR(26) TFR(6)
  x0 += ks2; x1 += ks0 + 5u;
#undef TFR
  o0 = x0; o1 = x1;
}

__device__ __forceinline__ float gumbel_from_bits(uint32_t b) {
  // uniform(minval=tiny, maxval=1); precise logf for both logs (winning
  // gumbels live at u~1 where fast-log relative accuracy is poorest).
  float u = __uint_as_float((b >> 9) | 0x3F800000u) - 1.0f;
  u = fmaxf(u, 1.17549435e-38f);
  return -logf(-logf(u));
}

// 4x4 outer-product FMA block; per-output strict sequential fmaf chain --
// accumulation order across c is EXACTLY c ascending (bit-identical policy).
#define FMA16(acc, av, bv) do { \
  acc[0][0]=fmaf(av.x,bv.x,acc[0][0]); acc[0][1]=fmaf(av.x,bv.y,acc[0][1]); \
  acc[0][2]=fmaf(av.x,bv.z,acc[0][2]); acc[0][3]=fmaf(av.x,bv.w,acc[0][3]); \
  acc[1][0]=fmaf(av.y,bv.x,acc[1][0]); acc[1][1]=fmaf(av.y,bv.y,acc[1][1]); \
  acc[1][2]=fmaf(av.y,bv.z,acc[1][2]); acc[1][3]=fmaf(av.y,bv.w,acc[1][3]); \
  acc[2][0]=fmaf(av.z,bv.x,acc[2][0]); acc[2][1]=fmaf(av.z,bv.y,acc[2][1]); \
  acc[2][2]=fmaf(av.z,bv.z,acc[2][2]); acc[2][3]=fmaf(av.z,bv.w,acc[2][3]); \
  acc[3][0]=fmaf(av.w,bv.x,acc[3][0]); acc[3][1]=fmaf(av.w,bv.y,acc[3][1]); \
  acc[3][2]=fmaf(av.w,bv.z,acc[3][2]); acc[3][3]=fmaf(av.w,bv.w,acc[3][3]); \
} while (0)

// ---------------------------------------------------------------------------
// Kernel 1: k = codebook @ wk^T, v = codebook @ wv^T   [1024 x 192 each]
// (unchanged from round 2 -- bit-identical km/vm)
// ---------------------------------------------------------------------------
__global__ __launch_bounds__(192) void kv_kernel(
    const float* __restrict__ cb, const float* __restrict__ wk,
    const float* __restrict__ wv, float* __restrict__ km, float* __restrict__ vm) {
  __shared__ float4 row[48];
  const int j = blockIdx.x;
  const int o = threadIdx.x;
  if (o < 48) row[o] = reinterpret_cast<const float4*>(cb + (size_t)j * CIN)[o];
  __syncthreads();
  const float4* wkr = reinterpret_cast<const float4*>(wk + (size_t)o * CIN);
  const float4* wvr = reinterpret_cast<const float4*>(wv + (size_t)o * CIN);
  float sk = 0.f, sv = 0.f;
#pragma unroll 8
  for (int c = 0; c < 48; ++c) {
    float4 a = row[c];
    float4 b = wkr[c];
    float4 w = wvr[c];
    sk = fmaf(a.x, b.x, sk); sk = fmaf(a.y, b.y, sk);
    sk = fmaf(a.z, b.z, sk); sk = fmaf(a.w, b.w, sk);
    sv = fmaf(a.x, w.x, sv); sv = fmaf(a.y, w.y, sv);
    sv = fmaf(a.z, w.z, sv); sv = fmaf(a.w, w.w, sv);
  }
  km[(size_t)j * COUT + o] = sk;
  vm[(size_t)j * COUT + o] = sv;
}

// ---------------------------------------------------------------------------
// Kernel 2 (fully fused): q GEMM -> logit GEMM + gumbel + dual argmax + gather
// 512 blocks x 256 threads (exactly 2 blocks/CU, zero tail).
// Phase 1: qT tile [192o x 64p] computed into aT (fmaf chain identical to the
//          old q_kernel -> bit-identical q).
// Phase 2: logit GEMM with double-buffered km staging (1 barrier/chunk,
//          global loads issued before the barrier), identical numerics.
// ---------------------------------------------------------------------------
__global__ __launch_bounds__(256, 2) void fused_kernel(
    const float* __restrict__ latent, const float* __restrict__ wq,
    const float* __restrict__ km, const float* __restrict__ vm,
    const float* __restrict__ t1p, float* __restrict__ logit_out,
    float* __restrict__ code_out, float* __restrict__ quant_out) {
  __shared__ float aT[CIN][68];    // qT tile [o][p]: 52.2 KB
  __shared__ float bT[2][32][68];  // staging (lat/wq in ph1, km dbuf in ph2): 17.4 KB
  __shared__ float wLv[64][4];
  __shared__ int   wLi[64][4];
  __shared__ float wSv[64][4];
  __shared__ int   wSi[64][4];
  __shared__ int   sIdx[64];

  const int tid = threadIdx.x;
  const int p0 = blockIdx.x * 64;
  const int n = p0 >> 12, hw0 = p0 & 4095;
  const float t1 = t1p[0];
  const int tp = tid & 15;  // pixel frag: rows 4tp..4tp+3
  const int to = tid >> 4;  // output frag: cols 4to..4to+3

  // ---- Phase 1: q ----
  {
    const float4* lat4 =
        reinterpret_cast<const float4*>(latent + (size_t)n * (CIN * HWSZ));
    const float4* wq4 = reinterpret_cast<const float4*>(wq);
    const int hw40 = hw0 >> 2;
    const int lf = tid & 15, lr = tid >> 4;  // latent stage: f4-col, row
    const int wc4 = tid & 7, wr = tid >> 3;  // wq stage: f4-col, row
    for (int ot = 0; ot < 3; ++ot) {
      const int o0 = ot * 64;
      float acc[4][4] = {};
      for (int c0 = 0; c0 < CIN; c0 += 32) {
        // issue global loads before the guard barrier (latency overlap)
        float4 l0 = lat4[(size_t)(c0 + lr) * (HWSZ / 4) + hw40 + lf];
        float4 l1 = lat4[(size_t)(c0 + lr + 16) * (HWSZ / 4) + hw40 + lf];
        float4 w0 = wq4[(size_t)(o0 + wr) * (CIN / 4) + (c0 >> 2) + wc4];
        float4 w1 = wq4[(size_t)(o0 + wr + 32) * (CIN / 4) + (c0 >> 2) + wc4];
        __syncthreads();  // previous chunk's reads done
        *reinterpret_cast<float4*>(&bT[0][lr][4 * lf]) = l0;       // latT[c][p]
        *reinterpret_cast<float4*>(&bT[0][lr + 16][4 * lf]) = l1;
        bT[1][4 * wc4 + 0][wr] = w0.x; bT[1][4 * wc4 + 1][wr] = w0.y;  // wqT[c][o]
        bT[1][4 * wc4 + 2][wr] = w0.z; bT[1][4 * wc4 + 3][wr] = w0.w;
        bT[1][4 * wc4 + 0][wr + 32] = w1.x; bT[1][4 * wc4 + 1][wr + 32] = w1.y;
        bT[1][4 * wc4 + 2][wr + 32] = w1.z; bT[1][4 * wc4 + 3][wr + 32] = w1.w;
        __syncthreads();
#pragma unroll
        for (int c = 0; c < 32; ++c) {
          float4 av = *reinterpret_cast<const float4*>(&bT[0][c][4 * tp]);
          float4 bv = *reinterpret_cast<const float4*>(&bT[1][c][4 * to]);
          FMA16(acc, av, bv);
        }
      }
      // qT into aT: aT[o][p]
#pragma unroll
      for (int ii = 0; ii < 4; ++ii)
#pragma unroll
        for (int kk = 0; kk < 4; ++kk)
          aT[o0 + 4 * to + kk][4 * tp + ii] = acc[ii][kk];
    }
  }

  // ---- Phase 2: logit + gumbel + argmax ----
  float Lv[4], Sv[4];
  int Li[4], Si[4];
#pragma unroll
  for (int ii = 0; ii < 4; ++ii) {
    Lv[ii] = -INFINITY; Sv[ii] = -INFINITY; Li[ii] = 0; Si[ii] = 0;
  }

  const float4* km4 = reinterpret_cast<const float4*>(km);
  const int sc4 = tid & 7, sjj = tid >> 3;  // km stage: f4-col, row

  // prologue: chunk 0 (jt=0, c0=0) into bT[0]
  {
    float4 n0 = km4[(size_t)sjj * 48 + sc4];
    float4 n1 = km4[(size_t)(sjj + 32) * 48 + sc4];
    __syncthreads();  // phase-1 reads of bT done
    bT[0][4 * sc4 + 0][sjj] = n0.x; bT[0][4 * sc4 + 1][sjj] = n0.y;
    bT[0][4 * sc4 + 2][sjj] = n0.z; bT[0][4 * sc4 + 3][sjj] = n0.w;
    bT[0][4 * sc4 + 0][sjj + 32] = n1.x; bT[0][4 * sc4 + 1][sjj + 32] = n1.y;
    bT[0][4 * sc4 + 2][sjj + 32] = n1.z; bT[0][4 * sc4 + 3][sjj + 32] = n1.w;
  }

  for (int jt = 0; jt < 16; ++jt) {
    float acc[4][4] = {};
    for (int ci = 0; ci < 6; ++ci) {
      const int k = jt * 6 + ci;
      float4 n0, n1;
      const bool pref = (k + 1 < 96);
      if (pref) {  // issue next chunk's global loads early
        const int njt = (k + 1) / 6, nc0 = ((k + 1) % 6) * 32;
        n0 = km4[(size_t)(njt * 64 + sjj) * 48 + (nc0 >> 2) + sc4];
        n1 = km4[(size_t)(njt * 64 + sjj + 32) * 48 + (nc0 >> 2) + sc4];
      }
      __syncthreads();  // bT[k&1] writes visible; bT[(k+1)&1] readers done
      const int c0 = ci * 32;
      const int cur = k & 1;
#pragma unroll
      for (int c = 0; c < 32; ++c) {
        float4 av = *reinterpret_cast<const float4*>(&aT[c0 + c][4 * tp]);
        float4 bv = *reinterpret_cast<const float4*>(&bT[cur][c][4 * to]);
        FMA16(acc, av, bv);
      }
      if (pref) {
        const int b = cur ^ 1;
        bT[b][4 * sc4 + 0][sjj] = n0.x; bT[b][4 * sc4 + 1][sjj] = n0.y;
        bT[b][4 * sc4 + 2][sjj] = n0.z; bT[b][4 * sc4 + 3][sjj] = n0.w;
        bT[b][4 * sc4 + 0][sjj + 32] = n1.x; bT[b][4 * sc4 + 1][sjj + 32] = n1.y;
        bT[b][4 * sc4 + 2][sjj + 32] = n1.z; bT[b][4 * sc4 + 3][sjj + 32] = n1.w;
      }
    }
    // epilogue: scale exactly as ref (/scale then *t1), write logit,
    // update both running argmaxes with the exact gumbel stream
#pragma unroll
    for (int ii = 0; ii < 4; ++ii) {
      const int p = p0 + 4 * tp + ii;
      const int jb = jt * 64 + 4 * to;
      float4 lv;
      lv.x = acc[ii][0] / LOGIT_SCALE_F * t1;
      lv.y = acc[ii][1] / LOGIT_SCALE_F * t1;
      lv.z = acc[ii][2] / LOGIT_SCALE_F * t1;
      lv.w = acc[ii][3] / LOGIT_SCALE_F * t1;
      *reinterpret_cast<float4*>(logit_out + (size_t)p * KCB + jb) = lv;
      float vals[4] = {lv.x, lv.y, lv.z, lv.w};
#pragma unroll
      for (int jj = 0; jj < 4; ++jj) {
        const int jgl = jb + jj;
        const float val = vals[jj];
        if (val > Lv[ii]) { Lv[ii] = val; Li[ii] = jgl; }  // j ascending -> first-wins
        uint32_t b0, b1;
        threefry_0_42(0u, (uint32_t)p * (uint32_t)KCB + (uint32_t)jgl, b0, b1);
        const float s = val + gumbel_from_bits(b0 ^ b1);
        if (s > Sv[ii]) { Sv[ii] = s; Si[ii] = jgl; }
      }
    }
  }

  // in-wave reduce: lanes {tp, tp+16, tp+32, tp+48} share pixel rows
  {
    const int lane = tid & 63;
    const int wvid = tid >> 6;  // wave 0..3
#pragma unroll
    for (int ii = 0; ii < 4; ++ii) {
      float v = Lv[ii]; int idx = Li[ii];
      float s = Sv[ii]; int sidx = Si[ii];
#pragma unroll
      for (int m = 16; m <= 32; m <<= 1) {
        float v2 = __shfl_xor(v, m); int i2 = __shfl_xor(idx, m);
        if (v2 > v || (v2 == v && i2 < idx)) { v = v2; idx = i2; }
        float s2 = __shfl_xor(s, m); int j2 = __shfl_xor(sidx, m);
        if (s2 > s || (s2 == s && j2 < sidx)) { s = s2; sidx = j2; }
      }
      if (lane < 16) {
        const int r = 4 * tp + ii;
        wLv[r][wvid] = v; wLi[r][wvid] = idx;
        wSv[r][wvid] = s; wSi[r][wvid] = sidx;
      }
    }
  }
  __syncthreads();
  if (tid < 64) {
    const int r = tid;
    float bv = wLv[r][0]; int bi = wLi[r][0];
    float sv = wSv[r][0]; int si = wSi[r][0];
#pragma unroll
    for (int t = 1; t < 4; ++t) {
      float v1 = wLv[r][t]; int i1 = wLi[r][t];
      if (v1 > bv || (v1 == bv && i1 < bi)) { bv = v1; bi = i1; }
      float v2 = wSv[r][t]; int i2 = wSi[r][t];
      if (v2 > sv || (v2 == sv && i2 < si)) { sv = v2; si = i2; }
    }
    code_out[p0 + r] = (float)bi;
    sIdx[r] = si;
  }
  __syncthreads();

  // quantized[n][d][hw] = v[idx[p]][d]; lanes = 64 consecutive pixels
  {
    const int l = tid & 63, dg = tid >> 6;
    const int p = p0 + l;
    const int nn = p >> 12, hw = p & 4095;
    const int jv = sIdx[l];
    const float* vrow = vm + (size_t)jv * COUT;
    float* qb = quant_out + (size_t)nn * (COUT * HWSZ) + hw;
#pragma unroll
    for (int it = 0; it < 48; ++it) {
      const int d = it * 4 + dg;
      qb[(size_t)d * HWSZ] = vrow[d];
    }
  }
}

// ---------------------------------------------------------------------------
extern "C" void kernel_launch(void* const* d_in, const int* in_sizes, int n_in,
                              void* d_out, int out_size, void* d_ws, size_t ws_size,
                              hipStream_t stream) {
  (void)in_sizes; (void)n_in; (void)out_size; (void)ws_size;
  const float* latent   = (const float*)d_in[0];
  const float* codebook = (const float*)d_in[1];
  const float* wq       = (const float*)d_in[2];
  const float* wk       = (const float*)d_in[3];
  const float* wv       = (const float*)d_in[4];
  const float* t1       = (const float*)d_in[5];
  // d_in[6] = temperature (int, ==1): positive scalar, cannot change outputs

  float* ws = (float*)d_ws;
  float* km = ws;               // 196,608 floats
  float* vm = ws + 196608;      // 196,608 floats  (total ws use: 1.57 MB)

  float* quant = (float*)d_out;          // 6,291,456
  float* code  = quant + 6291456;        //    32,768
  float* logit = code + 32768;           // 33,554,432

  kv_kernel<<<dim3(KCB), dim3(192), 0, stream>>>(codebook, wk, wv, km, vm);
  fused_kernel<<<dim3(NPIX / 64), dim3(256), 0, stream>>>(
      latent, wq, km, vm, t1, logit, code, quant);
}

// Round 4
// 637.828 us; speedup vs baseline: 1.3676x; 1.3676x over previous
//
#include <hip/hip_runtime.h>
#include <cstdint>
#include <cstddef>

// Problem constants
#define CIN   192
#define COUT  192
#define KCB   1024
#define HWSZ  4096            // 64*64
#define NPIX  32768           // 8*64*64
#define LOGIT_SCALE_F 13.856406460551018f

// q tile is stashed in the logit region of d_out, cols [832,1024) of each
// pixel's 1024-wide row (proven in round 2). d_ws holds only km/vm (1.57 MB).
#define QCOL0 832

// ---------------------------------------------------------------------------
// JAX threefry2x32 (key = (0,42)), partitionable stream: bits(i) = o0 ^ o1 of
// threefry2x32((k1,k2), (0, i))  [validated rounds 1-3: argmax-exact]
// ---------------------------------------------------------------------------
__device__ __forceinline__ void threefry_0_42(uint32_t x0, uint32_t x1,
                                              uint32_t& o0, uint32_t& o1) {
  const uint32_t ks0 = 0u;
  const uint32_t ks1 = 42u;
  const uint32_t ks2 = 0x1BD11BDAu ^ 0u ^ 42u;
  x0 += ks0; x1 += ks1;
#define TFR(r) { x0 += x1; x1 = (x1 << (r)) | (x1 >> (32 - (r))); x1 ^= x0; }
  TFR(13) TFR(15) TFR(26) TFR(6)
  x0 += ks1; x1 += ks2 + 1u;
  TFR(17) TFR(29) TFR(16) TFR(24)
  x0 += ks2; x1 += ks0 + 2u;
  TFR(13) TFR(15) TFR(26) TFR(6)
  x0 += ks0; x1 += ks1 + 3u;
  TFR(17) TFR(29) TFR(16) TFR(24)
  x0 += ks1; x1 += ks2 + 4u;
  TFR(13) TFR(15) TFR(26) TFR(6)
  x0 += ks2; x1 += ks0 + 5u;
#undef TFR
  o0 = x0; o1 = x1;
}

__device__ __forceinline__ float gumbel_from_bits(uint32_t b) {
  float u = __uint_as_float((b >> 9) | 0x3F800000u) - 1.0f;
  u = fmaxf(u, 1.17549435e-38f);
  return -logf(-logf(u));
}

// 4x4 outer-product FMA block; per-output strict sequential fmaf chain --
// accumulation order across c is EXACTLY c ascending (bit-identical policy).
#define FMA16(acc, av, bv) do { \
  acc[0][0]=fmaf(av.x,bv.x,acc[0][0]); acc[0][1]=fmaf(av.x,bv.y,acc[0][1]); \
  acc[0][2]=fmaf(av.x,bv.z,acc[0][2]); acc[0][3]=fmaf(av.x,bv.w,acc[0][3]); \
  acc[1][0]=fmaf(av.y,bv.x,acc[1][0]); acc[1][1]=fmaf(av.y,bv.y,acc[1][1]); \
  acc[1][2]=fmaf(av.y,bv.z,acc[1][2]); acc[1][3]=fmaf(av.y,bv.w,acc[1][3]); \
  acc[2][0]=fmaf(av.z,bv.x,acc[2][0]); acc[2][1]=fmaf(av.z,bv.y,acc[2][1]); \
  acc[2][2]=fmaf(av.z,bv.z,acc[2][2]); acc[2][3]=fmaf(av.z,bv.w,acc[2][3]); \
  acc[3][0]=fmaf(av.w,bv.x,acc[3][0]); acc[3][1]=fmaf(av.w,bv.y,acc[3][1]); \
  acc[3][2]=fmaf(av.w,bv.z,acc[3][2]); acc[3][3]=fmaf(av.w,bv.w,acc[3][3]); \
} while (0)

// ---------------------------------------------------------------------------
// Kernel 1: k = codebook @ wk^T, v = codebook @ wv^T  (unchanged, bit-exact)
// ---------------------------------------------------------------------------
__global__ __launch_bounds__(192) void kv_kernel(
    const float* __restrict__ cb, const float* __restrict__ wk,
    const float* __restrict__ wv, float* __restrict__ km, float* __restrict__ vm) {
  __shared__ float4 row[48];
  const int j = blockIdx.x;
  const int o = threadIdx.x;
  if (o < 48) row[o] = reinterpret_cast<const float4*>(cb + (size_t)j * CIN)[o];
  __syncthreads();
  const float4* wkr = reinterpret_cast<const float4*>(wk + (size_t)o * CIN);
  const float4* wvr = reinterpret_cast<const float4*>(wv + (size_t)o * CIN);
  float sk = 0.f, sv = 0.f;
#pragma unroll 8
  for (int c = 0; c < 48; ++c) {
    float4 a = row[c];
    float4 b = wkr[c];
    float4 w = wvr[c];
    sk = fmaf(a.x, b.x, sk); sk = fmaf(a.y, b.y, sk);
    sk = fmaf(a.z, b.z, sk); sk = fmaf(a.w, b.w, sk);
    sv = fmaf(a.x, w.x, sv); sv = fmaf(a.y, w.y, sv);
    sv = fmaf(a.z, w.z, sv); sv = fmaf(a.w, w.w, sv);
  }
  km[(size_t)j * COUT + o] = sk;
  vm[(size_t)j * COUT + o] = sv;
}

// ---------------------------------------------------------------------------
// Kernel 2: q[p][o] = sum_c latent[n][c][hw] * wq[o][c] -> stash in logit cols
// [QCOL0, QCOL0+192). c-chunks of 32, single-barrier double-buffered staging.
// Accumulation strictly c-ascending => q bit-identical to rounds 1-2.
// ---------------------------------------------------------------------------
__global__ __launch_bounds__(256) void q_kernel(
    const float* __restrict__ latent, const float* __restrict__ wq,
    float* __restrict__ logitq) {
  __shared__ float sA[2][32][68];  // latT [c][p]
  __shared__ float sB[2][32][68];  // wqT  [c][o]
  const int tid = threadIdx.x;
  const int p0 = blockIdx.x * 64;
  const int o0 = blockIdx.y * 64;
  const int n = p0 >> 12, hw0 = p0 & 4095;
  const float4* lat4 =
      reinterpret_cast<const float4*>(latent + (size_t)n * (CIN * HWSZ));
  const float4* wq4 = reinterpret_cast<const float4*>(wq);
  const int hw40 = hw0 >> 2;
  const int lf = tid & 15, lr = tid >> 4;  // latent stage: f4-col, row
  const int wc4 = tid & 7, wr = tid >> 3;  // wq stage: f4-col, row
  const int tp = tid & 15, to = tid >> 4;
  float acc[4][4] = {};

  // prologue: chunk 0 into buffer 0 (no prior readers -> no barrier needed
  // before the writes; the loop's first barrier orders writes->reads)
  {
    float4 l0 = lat4[(size_t)lr * (HWSZ / 4) + hw40 + lf];
    float4 l1 = lat4[(size_t)(lr + 16) * (HWSZ / 4) + hw40 + lf];
    float4 w0 = wq4[(size_t)(o0 + wr) * (CIN / 4) + wc4];
    float4 w1 = wq4[(size_t)(o0 + wr + 32) * (CIN / 4) + wc4];
    *reinterpret_cast<float4*>(&sA[0][lr][4 * lf]) = l0;
    *reinterpret_cast<float4*>(&sA[0][lr + 16][4 * lf]) = l1;
    sB[0][4 * wc4 + 0][wr] = w0.x; sB[0][4 * wc4 + 1][wr] = w0.y;
    sB[0][4 * wc4 + 2][wr] = w0.z; sB[0][4 * wc4 + 3][wr] = w0.w;
    sB[0][4 * wc4 + 0][wr + 32] = w1.x; sB[0][4 * wc4 + 1][wr + 32] = w1.y;
    sB[0][4 * wc4 + 2][wr + 32] = w1.z; sB[0][4 * wc4 + 3][wr + 32] = w1.w;
  }

  for (int ci = 0; ci < 6; ++ci) {
    __syncthreads();  // chunk ci writes visible; buffer (ci+1)&1 readers done
    float4 l0, l1, w0, w1;
    const bool pref = (ci + 1 < 6);
    if (pref) {  // issue next chunk's loads; latency hides under the FMAs
      const int nc0 = (ci + 1) * 32;
      l0 = lat4[(size_t)(nc0 + lr) * (HWSZ / 4) + hw40 + lf];
      l1 = lat4[(size_t)(nc0 + lr + 16) * (HWSZ / 4) + hw40 + lf];
      w0 = wq4[(size_t)(o0 + wr) * (CIN / 4) + (nc0 >> 2) + wc4];
      w1 = wq4[(size_t)(o0 + wr + 32) * (CIN / 4) + (nc0 >> 2) + wc4];
    }
    const int cur = ci & 1;
#pragma unroll
    for (int c = 0; c < 32; ++c) {
      float4 av = *reinterpret_cast<const float4*>(&sA[cur][c][4 * tp]);
      float4 bv = *reinterpret_cast<const float4*>(&sB[cur][c][4 * to]);
      FMA16(acc, av, bv);
    }
    if (pref) {
      const int b = cur ^ 1;
      *reinterpret_cast<float4*>(&sA[b][lr][4 * lf]) = l0;
      *reinterpret_cast<float4*>(&sA[b][lr + 16][4 * lf]) = l1;
      sB[b][4 * wc4 + 0][wr] = w0.x; sB[b][4 * wc4 + 1][wr] = w0.y;
      sB[b][4 * wc4 + 2][wr] = w0.z; sB[b][4 * wc4 + 3][wr] = w0.w;
      sB[b][4 * wc4 + 0][wr + 32] = w1.x; sB[b][4 * wc4 + 1][wr + 32] = w1.y;
      sB[b][4 * wc4 + 2][wr + 32] = w1.z; sB[b][4 * wc4 + 3][wr + 32] = w1.w;
    }
  }
#pragma unroll
  for (int ii = 0; ii < 4; ++ii) {
    float4 w;
    w.x = acc[ii][0]; w.y = acc[ii][1]; w.z = acc[ii][2]; w.w = acc[ii][3];
    *reinterpret_cast<float4*>(
        logitq + (size_t)(p0 + 4 * tp + ii) * KCB + QCOL0 + o0 + 4 * to) = w;
  }
}

// ---------------------------------------------------------------------------
// Kernel 3 (fused): logit GEMM + gumbel + dual argmax + V gather.
// Round-2 proven structure; delta: single-barrier double-buffered km staging
// (97 barriers/block vs 192). Numerics bit-identical to round 2.
// ---------------------------------------------------------------------------
__global__ __launch_bounds__(256) void logit_kernel(
    const float* __restrict__ km, const float* __restrict__ vm,
    const float* __restrict__ t1p, float* __restrict__ logit_out,
    float* __restrict__ code_out, float* __restrict__ quant_out) {
  __shared__ float aT[CIN][68];    // [c][p] full-K resident: 52.2 KB
  __shared__ float bT[2][32][68];  // km chunk double-buffer: 17.4 KB
  __shared__ float wLv[64][4];
  __shared__ int   wLi[64][4];
  __shared__ float wSv[64][4];
  __shared__ int   wSi[64][4];
  __shared__ int   sIdx[64];

  const int tid = threadIdx.x;
  const int p0 = blockIdx.x * 64;
  const float t1 = t1p[0];

  // stage A: q rows p0..p0+63 from logit[:, QCOL0:QCOL0+192], transposed
  for (int i = 0; i < 12; ++i) {
    int flat = tid + i * 256;           // 0..3071
    int r = flat / 48, c4 = flat % 48;  // row, float4-col
    float4 v = reinterpret_cast<const float4*>(
        logit_out + (size_t)(p0 + r) * KCB + QCOL0)[c4];
    aT[c4 * 4 + 0][r] = v.x;
    aT[c4 * 4 + 1][r] = v.y;
    aT[c4 * 4 + 2][r] = v.z;
    aT[c4 * 4 + 3][r] = v.w;
  }

  const int tp = tid & 15;  // pixel frag: rows 4tp..4tp+3
  const int to = tid >> 4;  // j frag within subtile: 4to..4to+3
  float Lv[4], Sv[4];
  int Li[4], Si[4];
#pragma unroll
  for (int ii = 0; ii < 4; ++ii) {
    Lv[ii] = -INFINITY; Sv[ii] = -INFINITY; Li[ii] = 0; Si[ii] = 0;
  }

  const float4* km4 = reinterpret_cast<const float4*>(km);
  const int sc4 = tid & 7, sjj = tid >> 3;  // km stage: f4-col, row

  // prologue: chunk 0 (jt=0, c0=0) into bT[0] (no prior readers)
  {
    float4 n0 = km4[(size_t)sjj * 48 + sc4];
    float4 n1 = km4[(size_t)(sjj + 32) * 48 + sc4];
    bT[0][4 * sc4 + 0][sjj] = n0.x; bT[0][4 * sc4 + 1][sjj] = n0.y;
    bT[0][4 * sc4 + 2][sjj] = n0.z; bT[0][4 * sc4 + 3][sjj] = n0.w;
    bT[0][4 * sc4 + 0][sjj + 32] = n1.x; bT[0][4 * sc4 + 1][sjj + 32] = n1.y;
    bT[0][4 * sc4 + 2][sjj + 32] = n1.z; bT[0][4 * sc4 + 3][sjj + 32] = n1.w;
  }

  for (int jt = 0; jt < 16; ++jt) {
    float acc[4][4] = {};
    for (int ci = 0; ci < 6; ++ci) {
      const int k = jt * 6 + ci;
      __syncthreads();  // chunk k writes visible; buffer (k+1)&1 readers done
      float4 n0, n1;
      const bool pref = (k + 1 < 96);
      if (pref) {  // issue next chunk's loads; latency hides under the FMAs
        const int njt = (k + 1) / 6, nc0 = ((k + 1) % 6) * 32;
        n0 = km4[(size_t)(njt * 64 + sjj) * 48 + (nc0 >> 2) + sc4];
        n1 = km4[(size_t)(njt * 64 + sjj + 32) * 48 + (nc0 >> 2) + sc4];
      }
      const int c0 = ci * 32;
      const int cur = k & 1;
#pragma unroll
      for (int c = 0; c < 32; ++c) {
        float4 av = *reinterpret_cast<const float4*>(&aT[c0 + c][4 * tp]);
        float4 bv = *reinterpret_cast<const float4*>(&bT[cur][c][4 * to]);
        FMA16(acc, av, bv);
      }
      if (pref) {
        const int b = cur ^ 1;
        bT[b][4 * sc4 + 0][sjj] = n0.x; bT[b][4 * sc4 + 1][sjj] = n0.y;
        bT[b][4 * sc4 + 2][sjj] = n0.z; bT[b][4 * sc4 + 3][sjj] = n0.w;
        bT[b][4 * sc4 + 0][sjj + 32] = n1.x; bT[b][4 * sc4 + 1][sjj + 32] = n1.y;
        bT[b][4 * sc4 + 2][sjj + 32] = n1.z; bT[b][4 * sc4 + 3][sjj + 32] = n1.w;
      }
    }
    // epilogue: scale exactly as ref (/scale then *t1), write logit,
    // update both running argmaxes with the exact gumbel stream
#pragma unroll
    for (int ii = 0; ii < 4; ++ii) {
      const int p = p0 + 4 * tp + ii;
      const int jb = jt * 64 + 4 * to;
      float4 lv;
      lv.x = acc[ii][0] / LOGIT_SCALE_F * t1;
      lv.y = acc[ii][1] / LOGIT_SCALE_F * t1;
      lv.z = acc[ii][2] / LOGIT_SCALE_F * t1;
      lv.w = acc[ii][3] / LOGIT_SCALE_F * t1;
      *reinterpret_cast<float4*>(logit_out + (size_t)p * KCB + jb) = lv;
      float vals[4] = {lv.x, lv.y, lv.z, lv.w};
#pragma unroll
      for (int jj = 0; jj < 4; ++jj) {
        const int jgl = jb + jj;
        const float val = vals[jj];
        if (val > Lv[ii]) { Lv[ii] = val; Li[ii] = jgl; }  // j ascending
        uint32_t b0, b1;
        threefry_0_42(0u, (uint32_t)p * (uint32_t)KCB + (uint32_t)jgl, b0, b1);
        const float s = val + gumbel_from_bits(b0 ^ b1);
        if (s > Sv[ii]) { Sv[ii] = s; Si[ii] = jgl; }
      }
    }
  }

  // in-wave reduce: lanes {tp, tp+16, tp+32, tp+48} share pixel rows
  {
    const int lane = tid & 63;
    const int wvid = tid >> 6;  // wave 0..3
#pragma unroll
    for (int ii = 0; ii < 4; ++ii) {
      float v = Lv[ii]; int idx = Li[ii];
      float s = Sv[ii]; int sidx = Si[ii];
#pragma unroll
      for (int m = 16; m <= 32; m <<= 1) {
        float v2 = __shfl_xor(v, m); int i2 = __shfl_xor(idx, m);
        if (v2 > v || (v2 == v && i2 < idx)) { v = v2; idx = i2; }
        float s2 = __shfl_xor(s, m); int j2 = __shfl_xor(sidx, m);
        if (s2 > s || (s2 == s && j2 < sidx)) { s = s2; sidx = j2; }
      }
      if (lane < 16) {
        const int r = 4 * tp + ii;
        wLv[r][wvid] = v; wLi[r][wvid] = idx;
        wSv[r][wvid] = s; wSi[r][wvid] = sidx;
      }
    }
  }
  __syncthreads();
  if (tid < 64) {
    const int r = tid;
    float bv = wLv[r][0]; int bi = wLi[r][0];
    float sv = wSv[r][0]; int si = wSi[r][0];
#pragma unroll
    for (int t = 1; t < 4; ++t) {
      float v1 = wLv[r][t]; int i1 = wLi[r][t];
      if (v1 > bv || (v1 == bv && i1 < bi)) { bv = v1; bi = i1; }
      float v2 = wSv[r][t]; int i2 = wSi[r][t];
      if (v2 > sv || (v2 == sv && i2 < si)) { sv = v2; si = i2; }
    }
    code_out[p0 + r] = (float)bi;
    sIdx[r] = si;
  }
  __syncthreads();

  // quantized[n][d][hw] = v[idx[p]][d]; lanes = 64 consecutive pixels
  {
    const int l = tid & 63, dg = tid >> 6;
    const int p = p0 + l;
    const int nn = p >> 12, hw = p & 4095;
    const int jv = sIdx[l];
    const float* vrow = vm + (size_t)jv * COUT;
    float* qb = quant_out + (size_t)nn * (COUT * HWSZ) + hw;
#pragma unroll
    for (int it = 0; it < 48; ++it) {
      const int d = it * 4 + dg;
      qb[(size_t)d * HWSZ] = vrow[d];
    }
  }
}

// ---------------------------------------------------------------------------
extern "C" void kernel_launch(void* const* d_in, const int* in_sizes, int n_in,
                              void* d_out, int out_size, void* d_ws, size_t ws_size,
                              hipStream_t stream) {
  (void)in_sizes; (void)n_in; (void)out_size; (void)ws_size;
  const float* latent   = (const float*)d_in[0];
  const float* codebook = (const float*)d_in[1];
  const float* wq       = (const float*)d_in[2];
  const float* wk       = (const float*)d_in[3];
  const float* wv       = (const float*)d_in[4];
  const float* t1       = (const float*)d_in[5];
  // d_in[6] = temperature (int, ==1): positive scalar, cannot change outputs

  float* ws = (float*)d_ws;
  float* km = ws;               // 196,608 floats
  float* vm = ws + 196608;      // 196,608 floats  (total ws use: 1.57 MB)

  float* quant = (float*)d_out;          // 6,291,456
  float* code  = quant + 6291456;        //    32,768
  float* logit = code + 32768;           // 33,554,432 (cols 832..1023 stage q)

  kv_kernel<<<dim3(KCB), dim3(192), 0, stream>>>(codebook, wk, wv, km, vm);
  q_kernel<<<dim3(NPIX / 64, CIN / 64), dim3(256), 0, stream>>>(latent, wq, logit);
  logit_kernel<<<dim3(NPIX / 64), dim3(256), 0, stream>>>(km, vm, t1, logit, code, quant);
}

// Round 5
// 534.367 us; speedup vs baseline: 1.6324x; 1.1936x over previous
//
#include <hip/hip_runtime.h>
#include <cstdint>
#include <cstddef>

// Problem constants
#define CIN   192
#define COUT  192
#define KCB   1024
#define HWSZ  4096            // 64*64
#define NPIX  32768           // 8*64*64
#define LOGIT_SCALE_F 13.856406460551018f

// q tile is stashed in the logit region of d_out, cols [832,1024) of each
// pixel's 1024-wide row (proven rounds 2-4). d_ws holds only km/vm (1.57 MB).
#define QCOL0 832

// ---------------------------------------------------------------------------
// JAX threefry2x32 (key = (0,42)), partitionable stream: bits(i) = o0 ^ o1 of
// threefry2x32((k1,k2), (0, i))  [validated rounds 1-4: argmax-exact]
// ---------------------------------------------------------------------------
__device__ __forceinline__ void threefry_0_42(uint32_t x0, uint32_t x1,
                                              uint32_t& o0, uint32_t& o1) {
  const uint32_t ks0 = 0u;
  const uint32_t ks1 = 42u;
  const uint32_t ks2 = 0x1BD11BDAu ^ 0u ^ 42u;
  x0 += ks0; x1 += ks1;
#define TFR(r) { x0 += x1; x1 = (x1 << (r)) | (x1 >> (32 - (r))); x1 ^= x0; }
  TFR(13) TFR(15) TFR(26) TFR(6)
  x0 += ks1; x1 += ks2 + 1u;
  TFR(17) TFR(29) TFR(16) TFR(24)
  x0 += ks2; x1 += ks0 + 2u;
  TFR(13) TFR(15) TFR(26) TFR(6)
  x0 += ks0; x1 += ks1 + 3u;
  TFR(17) TFR(29) TFR(16) TFR(24)
  x0 += ks1; x1 += ks2 + 4u;
  TFR(13) TFR(15) TFR(26) TFR(6)
  x0 += ks2; x1 += ks0 + 5u;
#undef TFR
  o0 = x0; o1 = x1;
}

__device__ __forceinline__ float gumbel_from_bits(uint32_t b) {
  float u = __uint_as_float((b >> 9) | 0x3F800000u) - 1.0f;
  u = fmaxf(u, 1.17549435e-38f);
  return -logf(-logf(u));
}

// 4x4 outer-product FMA block; per-output strict sequential fmaf chain --
// accumulation order across c is EXACTLY c ascending (bit-identical policy).
#define FMA16(acc, av, bv) do { \
  acc[0][0]=fmaf(av.x,bv.x,acc[0][0]); acc[0][1]=fmaf(av.x,bv.y,acc[0][1]); \
  acc[0][2]=fmaf(av.x,bv.z,acc[0][2]); acc[0][3]=fmaf(av.x,bv.w,acc[0][3]); \
  acc[1][0]=fmaf(av.y,bv.x,acc[1][0]); acc[1][1]=fmaf(av.y,bv.y,acc[1][1]); \
  acc[1][2]=fmaf(av.y,bv.z,acc[1][2]); acc[1][3]=fmaf(av.y,bv.w,acc[1][3]); \
  acc[2][0]=fmaf(av.z,bv.x,acc[2][0]); acc[2][1]=fmaf(av.z,bv.y,acc[2][1]); \
  acc[2][2]=fmaf(av.z,bv.z,acc[2][2]); acc[2][3]=fmaf(av.z,bv.w,acc[2][3]); \
  acc[3][0]=fmaf(av.w,bv.x,acc[3][0]); acc[3][1]=fmaf(av.w,bv.y,acc[3][1]); \
  acc[3][2]=fmaf(av.w,bv.z,acc[3][2]); acc[3][3]=fmaf(av.w,bv.w,acc[3][3]); \
} while (0)

// 1x8 FMA row: acc[k] += a * {b0,b1}[k], strict per-output chain
#define FMA8(accr, a, b0, b1) do { \
  accr[0]=fmaf(a,b0.x,accr[0]); accr[1]=fmaf(a,b0.y,accr[1]); \
  accr[2]=fmaf(a,b0.z,accr[2]); accr[3]=fmaf(a,b0.w,accr[3]); \
  accr[4]=fmaf(a,b1.x,accr[4]); accr[5]=fmaf(a,b1.y,accr[5]); \
  accr[6]=fmaf(a,b1.z,accr[6]); accr[7]=fmaf(a,b1.w,accr[7]); \
} while (0)

// ---------------------------------------------------------------------------
// Kernel 1: km = codebook @ wk^T, vm = codebook @ wv^T   [1024 x 192 each]
// Tiled GEMM rewrite: 48 blocks (16 j-tiles x 3 o-tiles), coalesced float4
// staging, both outputs per pass. Per-output fmaf chain strictly c-ascending
// => bit-identical to rounds 1-4 kv.
// ---------------------------------------------------------------------------
__global__ __launch_bounds__(256) void kv_kernel(
    const float* __restrict__ cb, const float* __restrict__ wk,
    const float* __restrict__ wv, float* __restrict__ km, float* __restrict__ vm) {
  __shared__ float sCb[32][68];  // cbT [c][j]
  __shared__ float sK[32][68];   // wkT [c][o]
  __shared__ float sV[32][68];   // wvT [c][o]
  const int tid = threadIdx.x;
  const int j0 = blockIdx.x * 64;
  const int o0 = blockIdx.y * 64;
  const float4* cb4 = reinterpret_cast<const float4*>(cb);
  const float4* wk4 = reinterpret_cast<const float4*>(wk);
  const float4* wv4 = reinterpret_cast<const float4*>(wv);
  const int c4 = tid & 7, rr = tid >> 3;  // f4-col (8 = 32c), row (32)
  const int tp = tid & 15, to = tid >> 4;
  float ak[4][4] = {};
  float av_[4][4] = {};

  for (int ci = 0; ci < 6; ++ci) {
    __syncthreads();  // previous chunk's readers done
    {
      const int cf = ci * 8 + c4;
#pragma unroll
      for (int pass = 0; pass < 2; ++pass) {
        const int r = rr + pass * 32;
        float4 a = cb4[(size_t)(j0 + r) * 48 + cf];
        float4 b = wk4[(size_t)(o0 + r) * 48 + cf];
        float4 c = wv4[(size_t)(o0 + r) * 48 + cf];
        sCb[4 * c4 + 0][r] = a.x; sCb[4 * c4 + 1][r] = a.y;
        sCb[4 * c4 + 2][r] = a.z; sCb[4 * c4 + 3][r] = a.w;
        sK[4 * c4 + 0][r] = b.x; sK[4 * c4 + 1][r] = b.y;
        sK[4 * c4 + 2][r] = b.z; sK[4 * c4 + 3][r] = b.w;
        sV[4 * c4 + 0][r] = c.x; sV[4 * c4 + 1][r] = c.y;
        sV[4 * c4 + 2][r] = c.z; sV[4 * c4 + 3][r] = c.w;
      }
    }
    __syncthreads();
#pragma unroll
    for (int c = 0; c < 32; ++c) {
      float4 a = *reinterpret_cast<const float4*>(&sCb[c][4 * tp]);
      float4 bk = *reinterpret_cast<const float4*>(&sK[c][4 * to]);
      float4 bv = *reinterpret_cast<const float4*>(&sV[c][4 * to]);
      FMA16(ak, a, bk);
      FMA16(av_, a, bv);
    }
  }
#pragma unroll
  for (int ii = 0; ii < 4; ++ii) {
    float4 w;
    w.x = ak[ii][0]; w.y = ak[ii][1]; w.z = ak[ii][2]; w.w = ak[ii][3];
    *reinterpret_cast<float4*>(km + (size_t)(j0 + 4 * tp + ii) * COUT + o0 + 4 * to) = w;
    float4 v;
    v.x = av_[ii][0]; v.y = av_[ii][1]; v.z = av_[ii][2]; v.w = av_[ii][3];
    *reinterpret_cast<float4*>(vm + (size_t)(j0 + 4 * tp + ii) * COUT + o0 + 4 * to) = v;
  }
}

// ---------------------------------------------------------------------------
// Kernel 2: q[p][o] = sum_c latent[n][c][hw] * wq[o][c] -> stash in logit cols
// [QCOL0, QCOL0+192). 32-c chunks, SINGLE-buffer, barrier;load;write;barrier
// discipline (no cross-barrier register carries). Chain strictly c-ascending
// => q bit-identical to rounds 1-4.
// ---------------------------------------------------------------------------
__global__ __launch_bounds__(256) void q_kernel(
    const float* __restrict__ latent, const float* __restrict__ wq,
    float* __restrict__ logitq) {
  __shared__ float sA[32][68];  // latT [c][p]
  __shared__ float sB[32][68];  // wqT  [c][o]
  const int tid = threadIdx.x;
  const int p0 = blockIdx.x * 64;
  const int o0 = blockIdx.y * 64;
  const int n = p0 >> 12, hw0 = p0 & 4095;
  const float4* lat4 =
      reinterpret_cast<const float4*>(latent + (size_t)n * (CIN * HWSZ));
  const float4* wq4 = reinterpret_cast<const float4*>(wq);
  const int hw40 = hw0 >> 2;
  const int lf = tid & 15, lr = tid >> 4;  // latent stage: f4-col (64p), row (16c)
  const int wc4 = tid & 7, wr = tid >> 3;  // wq stage: f4-col (32c), row (32o)
  const int tp = tid & 15, to = tid >> 4;
  float acc[4][4] = {};

  for (int ci = 0; ci < 6; ++ci) {
    const int c0 = ci * 32;
    __syncthreads();  // previous chunk's readers done
    {
      float4 l0 = lat4[(size_t)(c0 + lr) * (HWSZ / 4) + hw40 + lf];
      float4 l1 = lat4[(size_t)(c0 + lr + 16) * (HWSZ / 4) + hw40 + lf];
      float4 w0 = wq4[(size_t)(o0 + wr) * 48 + (c0 >> 2) + wc4];
      float4 w1 = wq4[(size_t)(o0 + wr + 32) * 48 + (c0 >> 2) + wc4];
      *reinterpret_cast<float4*>(&sA[lr][4 * lf]) = l0;
      *reinterpret_cast<float4*>(&sA[lr + 16][4 * lf]) = l1;
      sB[4 * wc4 + 0][wr] = w0.x; sB[4 * wc4 + 1][wr] = w0.y;
      sB[4 * wc4 + 2][wr] = w0.z; sB[4 * wc4 + 3][wr] = w0.w;
      sB[4 * wc4 + 0][wr + 32] = w1.x; sB[4 * wc4 + 1][wr + 32] = w1.y;
      sB[4 * wc4 + 2][wr + 32] = w1.z; sB[4 * wc4 + 3][wr + 32] = w1.w;
    }
    __syncthreads();
#pragma unroll
    for (int c = 0; c < 32; ++c) {
      float4 av = *reinterpret_cast<const float4*>(&sA[c][4 * tp]);
      float4 bv = *reinterpret_cast<const float4*>(&sB[c][4 * to]);
      FMA16(acc, av, bv);
    }
  }
#pragma unroll
  for (int ii = 0; ii < 4; ++ii) {
    float4 w;
    w.x = acc[ii][0]; w.y = acc[ii][1]; w.z = acc[ii][2]; w.w = acc[ii][3];
    *reinterpret_cast<float4*>(
        logitq + (size_t)(p0 + 4 * tp + ii) * KCB + QCOL0 + o0 + 4 * to) = w;
  }
}

// ---------------------------------------------------------------------------
// Kernel 3 (fused): logit GEMM + gumbel + dual argmax + V gather.
// 32-px x 128-j subtile, 1024 blocks: LDS 45.6 KB -> 3 blocks/CU (12 waves/CU
// vs round-2's 8), 96 barriers/block (vs 192). Staging discipline identical
// to round 2 (no cross-barrier reg carries). Per-(p,j) fmaf chain, gumbel
// stream, and tie-break logic bit-identical; only thread mapping changed.
// ---------------------------------------------------------------------------
__global__ __launch_bounds__(256) void logit_kernel(
    const float* __restrict__ km, const float* __restrict__ vm,
    const float* __restrict__ t1p, float* __restrict__ logit_out,
    float* __restrict__ code_out, float* __restrict__ quant_out) {
  __shared__ float aT[CIN][36];   // qT [c][p], 32 px: 27.0 KB
  __shared__ float bT[32][132];   // kmT chunk [c][j], 128 j: 16.5 KB
  __shared__ float wLv[32][4];
  __shared__ int   wLi[32][4];
  __shared__ float wSv[32][4];
  __shared__ int   wSi[32][4];
  __shared__ int   sIdx[32];

  const int tid = threadIdx.x;
  const int p0 = blockIdx.x * 32;
  const float t1 = t1p[0];

  // stage A: q rows p0..p0+31 from logit[:, QCOL0:QCOL0+192], transposed
  for (int i = 0; i < 6; ++i) {
    int flat = tid + i * 256;           // 0..1535
    int r = flat / 48, c4 = flat % 48;  // row (32), float4-col (48)
    float4 v = reinterpret_cast<const float4*>(
        logit_out + (size_t)(p0 + r) * KCB + QCOL0)[c4];
    aT[c4 * 4 + 0][r] = v.x;
    aT[c4 * 4 + 1][r] = v.y;
    aT[c4 * 4 + 2][r] = v.z;
    aT[c4 * 4 + 3][r] = v.w;
  }

  const int tp = tid & 15;  // pixel frag: rows 2tp, 2tp+1
  const int to = tid >> 4;  // j frag within subtile: 8to..8to+7
  float Lv[2], Sv[2];
  int Li[2], Si[2];
#pragma unroll
  for (int ii = 0; ii < 2; ++ii) {
    Lv[ii] = -INFINITY; Sv[ii] = -INFINITY; Li[ii] = 0; Si[ii] = 0;
  }

  const float4* km4 = reinterpret_cast<const float4*>(km);
  const int sc4 = tid & 7, sjj = tid >> 3;  // km stage: f4-col (32c), row (32j)

  for (int jt = 0; jt < 8; ++jt) {
    float acc[2][8] = {};
    for (int ci = 0; ci < 6; ++ci) {
      const int c0 = ci * 32;
      __syncthreads();  // previous chunk's bT readers done (covers aT on first)
      {
#pragma unroll
        for (int pass = 0; pass < 4; ++pass) {
          const int jloc = sjj + pass * 32;
          const int jg = jt * 128 + jloc;
          float4 v = km4[(size_t)jg * 48 + (c0 >> 2) + sc4];
          bT[4 * sc4 + 0][jloc] = v.x; bT[4 * sc4 + 1][jloc] = v.y;
          bT[4 * sc4 + 2][jloc] = v.z; bT[4 * sc4 + 3][jloc] = v.w;
        }
      }
      __syncthreads();
#pragma unroll
      for (int c = 0; c < 32; ++c) {
        float2 a2 = *reinterpret_cast<const float2*>(&aT[c0 + c][2 * tp]);
        float4 b0 = *reinterpret_cast<const float4*>(&bT[c][8 * to]);
        float4 b1 = *reinterpret_cast<const float4*>(&bT[c][8 * to + 4]);
        FMA8(acc[0], a2.x, b0, b1);
        FMA8(acc[1], a2.y, b0, b1);
      }
    }
    // epilogue: scale exactly as ref (/scale then *t1), write logit,
    // update both running argmaxes with the exact gumbel stream
#pragma unroll
    for (int ii = 0; ii < 2; ++ii) {
      const int p = p0 + 2 * tp + ii;
      const int jb = jt * 128 + 8 * to;
      float lv[8];
#pragma unroll
      for (int k = 0; k < 8; ++k) lv[k] = acc[ii][k] / LOGIT_SCALE_F * t1;
      float4 w0, w1;
      w0.x = lv[0]; w0.y = lv[1]; w0.z = lv[2]; w0.w = lv[3];
      w1.x = lv[4]; w1.y = lv[5]; w1.z = lv[6]; w1.w = lv[7];
      float* lrow = logit_out + (size_t)p * KCB + jb;
      *reinterpret_cast<float4*>(lrow) = w0;
      *reinterpret_cast<float4*>(lrow + 4) = w1;
#pragma unroll
      for (int jj = 0; jj < 8; ++jj) {
        const int jgl = jb + jj;
        const float val = lv[jj];
        if (val > Lv[ii]) { Lv[ii] = val; Li[ii] = jgl; }  // j ascending
        uint32_t b0, b1;
        threefry_0_42(0u, (uint32_t)p * (uint32_t)KCB + (uint32_t)jgl, b0, b1);
        const float s = val + gumbel_from_bits(b0 ^ b1);
        if (s > Sv[ii]) { Sv[ii] = s; Si[ii] = jgl; }
      }
    }
  }

  // in-wave reduce: lanes {tp, tp+16, tp+32, tp+48} share pixel rows
  {
    const int lane = tid & 63;
    const int wvid = tid >> 6;  // wave 0..3
#pragma unroll
    for (int ii = 0; ii < 2; ++ii) {
      float v = Lv[ii]; int idx = Li[ii];
      float s = Sv[ii]; int sidx = Si[ii];
#pragma unroll
      for (int m = 16; m <= 32; m <<= 1) {
        float v2 = __shfl_xor(v, m); int i2 = __shfl_xor(idx, m);
        if (v2 > v || (v2 == v && i2 < idx)) { v = v2; idx = i2; }
        float s2 = __shfl_xor(s, m); int j2 = __shfl_xor(sidx, m);
        if (s2 > s || (s2 == s && j2 < sidx)) { s = s2; sidx = j2; }
      }
      if (lane < 16) {
        const int r = 2 * tp + ii;
        wLv[r][wvid] = v; wLi[r][wvid] = idx;
        wSv[r][wvid] = s; wSi[r][wvid] = sidx;
      }
    }
  }
  __syncthreads();
  if (tid < 32) {
    const int r = tid;
    float bv = wLv[r][0]; int bi = wLi[r][0];
    float sv = wSv[r][0]; int si = wSi[r][0];
#pragma unroll
    for (int t = 1; t < 4; ++t) {
      float v1 = wLv[r][t]; int i1 = wLi[r][t];
      if (v1 > bv || (v1 == bv && i1 < bi)) { bv = v1; bi = i1; }
      float v2 = wSv[r][t]; int i2 = wSi[r][t];
      if (v2 > sv || (v2 == sv && i2 < si)) { sv = v2; si = i2; }
    }
    code_out[p0 + r] = (float)bi;
    sIdx[r] = si;
  }
  __syncthreads();

  // quantized[n][d][hw] = v[idx[p]][d]; lanes = 32 consecutive pixels
  {
    const int l = tid & 31, dg = tid >> 5;  // dg 0..7
    const int p = p0 + l;
    const int nn = p >> 12, hw = p & 4095;
    const int jv = sIdx[l];
    const float* vrow = vm + (size_t)jv * COUT;
    float* qb = quant_out + (size_t)nn * (COUT * HWSZ) + hw;
#pragma unroll
    for (int it = 0; it < 24; ++it) {
      const int d = it * 8 + dg;
      qb[(size_t)d * HWSZ] = vrow[d];
    }
  }
}

// ---------------------------------------------------------------------------
extern "C" void kernel_launch(void* const* d_in, const int* in_sizes, int n_in,
                              void* d_out, int out_size, void* d_ws, size_t ws_size,
                              hipStream_t stream) {
  (void)in_sizes; (void)n_in; (void)out_size; (void)ws_size;
  const float* latent   = (const float*)d_in[0];
  const float* codebook = (const float*)d_in[1];
  const float* wq       = (const float*)d_in[2];
  const float* wk       = (const float*)d_in[3];
  const float* wv       = (const float*)d_in[4];
  const float* t1       = (const float*)d_in[5];
  // d_in[6] = temperature (int, ==1): positive scalar, cannot change outputs

  float* ws = (float*)d_ws;
  float* km = ws;               // 196,608 floats
  float* vm = ws + 196608;      // 196,608 floats  (total ws use: 1.57 MB)

  float* quant = (float*)d_out;          // 6,291,456
  float* code  = quant + 6291456;        //    32,768
  float* logit = code + 32768;           // 33,554,432 (cols 832..1023 stage q)

  kv_kernel<<<dim3(16, 3), dim3(256), 0, stream>>>(codebook, wk, wv, km, vm);
  q_kernel<<<dim3(NPIX / 64, CIN / 64), dim3(256), 0, stream>>>(latent, wq, logit);
  logit_kernel<<<dim3(NPIX / 32), dim3(256), 0, stream>>>(km, vm, t1, logit, code, quant);
}